// Round 2
// 190.756 us; speedup vs baseline: 1.1596x; 1.1596x over previous
//
#include <hip/hip_runtime.h>

// MGNConv fused-MFMA version, round 1 of polish pass (resubmit after infra fail).
//   edge_out[e,k] = sum_{c,ab} hs[e,c] * o[e,ab] * w2[c, ab*8+k]
//   hs = silu(emb@w1/4)/64  (folds both 1/8 path norms)
//   o[e,ab] = attr[e, ab>>4] * z[e, ab&15],  z = cat(x[vi], x[vj])
// Changes this round:
//  - software-pipelined staging: ei prefetched 2 tiles ahead, x-gathers /
//    attr / emb 1 tile ahead (register-rotated in place: phase A consumes
//    regs into LDS, phase B reissues loads into the same regs)
//  - z / attr staged as f32 (no bf2f in the epilogue)
//  - defer-attr epilogue: tacc += c*zv per tile, eacc += av*tacc per g-group
//  - v_cvt_pk_bf16_f32 for hs store and a1 fragments (1 op / 2 values)
//  - silu uses v_rcp_f32 instead of precise f32 division
//  - s_setprio(1) around the main GEMM phase

typedef __attribute__((ext_vector_type(8))) short short8;
typedef __attribute__((ext_vector_type(4))) float floatx4;

__device__ inline unsigned short f2bf(float f) {
    union { float f; unsigned u; } v; v.f = f;
    unsigned r = v.u + 0x7FFFu + ((v.u >> 16) & 1u);
    return (unsigned short)(r >> 16);
}

__device__ inline unsigned cvt_pk_bf16(float lo, float hi) {
    unsigned r;
    asm("v_cvt_pk_bf16_f32 %0, %1, %2" : "=v"(r) : "v"(lo), "v"(hi));
    return r;
}

constexpr int TB   = 512;   // 8 waves
constexpr int NBLK = 256;   // 1 block per CU (LDS-limited)

// LDS strides. W2/HS rows are multiples of 8 bf16 (16 B) so ds_read_b128
// stays aligned; 72 = 16B*9 (odd multiple) de-clusters banks.
constexpr int W2_LD  = 72;  // [512][72] bf16
constexpr int HS_LD  = 72;  // per wave [32][72] bf16
constexpr int ZT_LDF = 48;  // per wave [16][48] f32 (48%32==16 -> the two
                            // broadcast rows (parity) hit disjoint bank halves)
constexpr int AT_LDF = 32;  // per wave [4][32] f32

__global__ __launch_bounds__(TB, 2) void edge_kernel(
    const float* __restrict__ x,          // [N,8]
    const int*   __restrict__ ei,         // [2,E]
    const float* __restrict__ attr,       // [E,4]
    const float* __restrict__ emb,        // [E,16]
    const float* __restrict__ w1,         // [16,64]
    const float* __restrict__ w2,         // [64,512]
    float* __restrict__ edge_out,         // [E,8]
    float* __restrict__ e_sum,            // [N,8] pre-zeroed
    int E)
{
    __shared__ __align__(16) unsigned short s_w2t[512 * W2_LD];   // 73728 B
    __shared__ __align__(16) unsigned short s_hsA[8 * 32 * HS_LD];// 36864 B
    __shared__ __align__(16) float          s_ztA[8 * 16 * ZT_LDF];// 24576 B
    __shared__ __align__(16) float          s_atA[8 * 4 * AT_LDF]; //  4096 B
    __shared__ int                          s_vjA[8 * 32];         //  1024 B

    const int tid  = threadIdx.x;
    const int wave = tid >> 6;
    const int lane = tid & 63;
    const int m16  = lane & 15;
    const int quad = lane >> 4;
    const int par  = m16 >> 3;

    // ---- stage w2 transposed to bf16: s_w2t[n][k] = w2[k][n] ----
    for (int idx = tid; idx < 512 * 64; idx += TB) {
        const int n = idx & 511, k = idx >> 9;
        s_w2t[n * W2_LD + k] = f2bf(w2[k * 512 + n]);
    }
    __syncthreads();   // only barrier; steady loop is wave-private

    // ---- layer-1 B fragments (w1) in registers, zero-padded K 16->32 ----
    short8 w1f[4];
    #pragma unroll
    for (int ct = 0; ct < 4; ++ct) {
        short8 f;
        if (quad < 2) {
            #pragma unroll
            for (int j = 0; j < 8; ++j)
                f[j] = (short)f2bf(w1[(quad * 8 + j) * 64 + ct * 16 + m16]);
        } else {
            #pragma unroll
            for (int j = 0; j < 8; ++j) f[j] = 0;
        }
        w1f[ct] = f;
    }

    unsigned short* hsw = s_hsA + wave * 32 * HS_LD;
    float*          ztw = s_ztA + wave * 16 * ZT_LDF;
    float*          atw = s_atA + wave * 4 * AT_LDF;
    int*            vjw = s_vjA + wave * 32;

    const int  wid = blockIdx.x * 8 + wave;
    const int  nw  = NBLK * 8;
    const int  ntiles = E >> 5;   // E divisible by 32 (800000)
    const bool stg = (quad < 2);
    const int  mst = quad * 16 + m16;   // meaningful when stg

    // ---- pipeline registers (valid on stg lanes) ----
    float4 xi0, xi1, xj0, xj1, a4;
    float4 em0a, em0b, em1a, em1b;
    int viN = 0, vjN = 0, vjC = 0;

    // ---- prologue: tile wid data + ei for tile wid+nw ----
    if (wid < ntiles && stg) {
        const int e0 = (wid << 5) + mst;
        const int vi = ei[e0];
        vjC = ei[E + e0];
        xi0 = *(const float4*)(x + (size_t)vi * 8);
        xi1 = *(const float4*)(x + (size_t)vi * 8 + 4);
        xj0 = *(const float4*)(x + (size_t)vjC * 8);
        xj1 = *(const float4*)(x + (size_t)vjC * 8 + 4);
        a4  = *(const float4*)(attr + (size_t)e0 * 4);
        const float* ep0 = emb + (size_t)((wid << 5) + m16) * 16 + quad * 8;
        em0a = *(const float4*)ep0;
        em0b = *(const float4*)(ep0 + 4);
        const float* ep1 = emb + (size_t)((wid << 5) + 16 + m16) * 16 + quad * 8;
        em1a = *(const float4*)ep1;
        em1b = *(const float4*)(ep1 + 4);
        const int t1 = (wid + nw < ntiles) ? (wid + nw) : wid;
        const int e1 = (t1 << 5) + mst;
        viN = ei[e1];
        vjN = ei[E + e1];
    }

    for (int tile = wid; tile < ntiles; tile += nw) {
        const int base = tile << 5;

        // ---- A: stage current tile (regs -> LDS, f32), build a1 frags ----
        if (stg) {
            ztw[ 0*ZT_LDF+mst]=xi0.x; ztw[ 1*ZT_LDF+mst]=xi0.y;
            ztw[ 2*ZT_LDF+mst]=xi0.z; ztw[ 3*ZT_LDF+mst]=xi0.w;
            ztw[ 4*ZT_LDF+mst]=xi1.x; ztw[ 5*ZT_LDF+mst]=xi1.y;
            ztw[ 6*ZT_LDF+mst]=xi1.z; ztw[ 7*ZT_LDF+mst]=xi1.w;
            ztw[ 8*ZT_LDF+mst]=xj0.x; ztw[ 9*ZT_LDF+mst]=xj0.y;
            ztw[10*ZT_LDF+mst]=xj0.z; ztw[11*ZT_LDF+mst]=xj0.w;
            ztw[12*ZT_LDF+mst]=xj1.x; ztw[13*ZT_LDF+mst]=xj1.y;
            ztw[14*ZT_LDF+mst]=xj1.z; ztw[15*ZT_LDF+mst]=xj1.w;
            atw[0*AT_LDF+mst]=a4.x;   atw[1*AT_LDF+mst]=a4.y;
            atw[2*AT_LDF+mst]=a4.z;   atw[3*AT_LDF+mst]=a4.w;
            vjw[mst] = vjC;
        }

        short8 a1[2];
        {
            union { short8 s8; unsigned u[4]; } uu;
            if (stg) {
                uu.u[0] = cvt_pk_bf16(em0a.x, em0a.y);
                uu.u[1] = cvt_pk_bf16(em0a.z, em0a.w);
                uu.u[2] = cvt_pk_bf16(em0b.x, em0b.y);
                uu.u[3] = cvt_pk_bf16(em0b.z, em0b.w);
            } else {
                uu.u[0]=0u; uu.u[1]=0u; uu.u[2]=0u; uu.u[3]=0u;
            }
            a1[0] = uu.s8;
            if (stg) {
                uu.u[0] = cvt_pk_bf16(em1a.x, em1a.y);
                uu.u[1] = cvt_pk_bf16(em1a.z, em1a.w);
                uu.u[2] = cvt_pk_bf16(em1b.x, em1b.y);
                uu.u[3] = cvt_pk_bf16(em1b.z, em1b.w);
            } else {
                uu.u[0]=0u; uu.u[1]=0u; uu.u[2]=0u; uu.u[3]=0u;
            }
            a1[1] = uu.s8;
        }

        // ---- B: issue next-tile loads into the just-consumed registers.
        // In-order issue makes the reg WAR safe; loads have the whole
        // compute phase (~2000 cyc) to land before next iteration's A.
        {
            const int tn     = tile + nw;
            const int tn_cl  = (tn  < ntiles) ? tn  : tile;
            const int tnn    = tn + nw;
            const int tnn_cl = (tnn < ntiles) ? tnn : tn_cl;
            if (stg) {
                const int en = (tn_cl << 5) + mst;
                vjC = vjN;   // vj of tile tn, needed at next A and E
                xi0 = *(const float4*)(x + (size_t)viN * 8);
                xi1 = *(const float4*)(x + (size_t)viN * 8 + 4);
                xj0 = *(const float4*)(x + (size_t)vjN * 8);
                xj1 = *(const float4*)(x + (size_t)vjN * 8 + 4);
                a4  = *(const float4*)(attr + (size_t)en * 4);
                const float* ep0 = emb + (size_t)((tn_cl << 5) + m16) * 16 + quad * 8;
                em0a = *(const float4*)ep0;
                em0b = *(const float4*)(ep0 + 4);
                const float* ep1 = emb + (size_t)((tn_cl << 5) + 16 + m16) * 16 + quad * 8;
                em1a = *(const float4*)ep1;
                em1b = *(const float4*)(ep1 + 4);
                const int enn = (tnn_cl << 5) + mst;
                viN = ei[enn];
                vjN = ei[E + enn];
            }
        }

        // ---- C: layer-1 MFMA -> silu -> hs (bf16, wave-private LDS) ----
        #pragma unroll
        for (int s = 0; s < 2; ++s) {
            #pragma unroll
            for (int ct = 0; ct < 4; ++ct) {
                floatx4 c = {0.f, 0.f, 0.f, 0.f};
                c = __builtin_amdgcn_mfma_f32_16x16x32_bf16(a1[s], w1f[ct], c, 0, 0, 0);
                float sv[4];
                #pragma unroll
                for (int r = 0; r < 4; ++r) {
                    const float u   = c[r] * 0.25f;               // /sqrt(16)
                    const float den = 1.f + __expf(-u);
                    sv[r] = u * __builtin_amdgcn_rcpf(den) * 0.015625f; // /64
                }
                const unsigned p01 = cvt_pk_bf16(sv[0], sv[1]);
                const unsigned p23 = cvt_pk_bf16(sv[2], sv[3]);
                const int col  = ct * 16 + m16;
                const int row0 = s * 16 + quad * 4;
                hsw[(row0 + 0) * HS_LD + col] = (unsigned short)p01;
                hsw[(row0 + 1) * HS_LD + col] = (unsigned short)(p01 >> 16);
                hsw[(row0 + 2) * HS_LD + col] = (unsigned short)p23;
                hsw[(row0 + 3) * HS_LD + col] = (unsigned short)(p23 >> 16);
            }
        }

        // ---- main GEMM A fragments (loop-invariant over N) ----
        short8 a2[2][2];
        #pragma unroll
        for (int s = 0; s < 2; ++s)
            #pragma unroll
            for (int q = 0; q < 2; ++q)
                a2[s][q] = *(const short8*)(hsw + (s * 16 + m16) * HS_LD + q * 32 + quad * 8);

        float eacc[2][4];
        #pragma unroll
        for (int s = 0; s < 2; ++s)
            #pragma unroll
            for (int r = 0; r < 4; ++r) eacc[s][r] = 0.f;

        // ---- D: N loop, defer-attr epilogue.
        // b_idx = (2t+par)&15 == (2tt+par)&15 (g-independent, 16g = 0 mod 16)
        __builtin_amdgcn_s_setprio(1);
        #pragma unroll 1
        for (int g = 0; g < 4; ++g) {
            float av[2][4];
            #pragma unroll
            for (int s = 0; s < 2; ++s) {
                const float4 a4v = *(const float4*)(atw + g * AT_LDF + s * 16 + quad * 4);
                av[s][0] = a4v.x; av[s][1] = a4v.y;
                av[s][2] = a4v.z; av[s][3] = a4v.w;
            }
            float tacc[2][4];
            #pragma unroll
            for (int s = 0; s < 2; ++s)
                #pragma unroll
                for (int r = 0; r < 4; ++r) tacc[s][r] = 0.f;

            #pragma unroll
            for (int tt = 0; tt < 8; ++tt) {
                const int t = g * 8 + tt;
                short8 b2[2];
                b2[0] = *(const short8*)(s_w2t + (16 * t + m16) * W2_LD + quad * 8);
                b2[1] = *(const short8*)(s_w2t + (16 * t + m16) * W2_LD + 32 + quad * 8);
                const int b_idx = (2 * tt + par) & 15;
                #pragma unroll
                for (int s = 0; s < 2; ++s) {
                    floatx4 c = {0.f, 0.f, 0.f, 0.f};
                    c = __builtin_amdgcn_mfma_f32_16x16x32_bf16(a2[s][0], b2[0], c, 0, 0, 0);
                    c = __builtin_amdgcn_mfma_f32_16x16x32_bf16(a2[s][1], b2[1], c, 0, 0, 0);
                    const float4 zv = *(const float4*)(ztw + b_idx * ZT_LDF + s * 16 + quad * 4);
                    tacc[s][0] = fmaf(c[0], zv.x, tacc[s][0]);
                    tacc[s][1] = fmaf(c[1], zv.y, tacc[s][1]);
                    tacc[s][2] = fmaf(c[2], zv.z, tacc[s][2]);
                    tacc[s][3] = fmaf(c[3], zv.w, tacc[s][3]);
                }
            }
            #pragma unroll
            for (int s = 0; s < 2; ++s)
                #pragma unroll
                for (int r = 0; r < 4; ++r)
                    eacc[s][r] = fmaf(av[s][r], tacc[s][r], eacc[s][r]);
        }
        __builtin_amdgcn_s_setprio(0);

        // ---- E: reduce ab-parity (lanes col and col^8), then write ----
        #pragma unroll
        for (int s = 0; s < 2; ++s)
            #pragma unroll
            for (int r = 0; r < 4; ++r)
                eacc[s][r] += __shfl_xor(eacc[s][r], 8, 64);

        if (m16 < 8) {
            #pragma unroll
            for (int s = 0; s < 2; ++s) {
                const int4 vjq = *(const int4*)(vjw + s * 16 + quad * 4);
                const int vjr[4] = {vjq.x, vjq.y, vjq.z, vjq.w};
                #pragma unroll
                for (int r = 0; r < 4; ++r) {
                    const int e = base + s * 16 + quad * 4 + r;
                    edge_out[(size_t)e * 8 + m16] = eacc[s][r];
                    atomicAdd(e_sum + (size_t)vjr[r] * 8 + m16, eacc[s][r]);
                }
            }
        }
    }
}

__global__ __launch_bounds__(256) void node_kernel(
    const float* __restrict__ x,       // [N,8]
    const float* __restrict__ e_sum,   // [N,8]
    const float* __restrict__ w_node,  // [8,8,16]
    float* __restrict__ x_out,         // [N,16]
    int N)
{
    __shared__ float s_w[8 * 8 * 16];
    for (int idx = threadIdx.x; idx < 1024; idx += 256) s_w[idx] = w_node[idx];
    __syncthreads();

    const int n = blockIdx.x * 256 + threadIdx.x;
    if (n >= N) return;

    float xa[8], eb[8];
    #pragma unroll
    for (int a = 0; a < 8; ++a) xa[a] = x[(size_t)n * 8 + a];
    #pragma unroll
    for (int b = 0; b < 8; ++b) eb[b] = e_sum[(size_t)n * 8 + b];

    float out[16];
    #pragma unroll
    for (int k = 0; k < 16; ++k) out[k] = 0.f;

    const float4* wv = (const float4*)s_w;
    #pragma unroll
    for (int a = 0; a < 8; ++a) {
        #pragma unroll
        for (int b = 0; b < 8; ++b) {
            const float t = xa[a] * eb[b] * 0.125f;
            #pragma unroll
            for (int k4 = 0; k4 < 4; ++k4) {
                const float4 w = wv[(a * 8 + b) * 4 + k4];
                out[k4 * 4 + 0] = fmaf(t, w.x, out[k4 * 4 + 0]);
                out[k4 * 4 + 1] = fmaf(t, w.y, out[k4 * 4 + 1]);
                out[k4 * 4 + 2] = fmaf(t, w.z, out[k4 * 4 + 2]);
                out[k4 * 4 + 3] = fmaf(t, w.w, out[k4 * 4 + 3]);
            }
        }
    }

    float4* xo = (float4*)(x_out + (size_t)n * 16);
    #pragma unroll
    for (int k4 = 0; k4 < 4; ++k4)
        xo[k4] = make_float4(out[k4 * 4 + 0], out[k4 * 4 + 1],
                             out[k4 * 4 + 2], out[k4 * 4 + 3]);
}

extern "C" void kernel_launch(void* const* d_in, const int* in_sizes, int n_in,
                              void* d_out, int out_size, void* d_ws, size_t ws_size,
                              hipStream_t stream) {
    const float* x      = (const float*)d_in[0];
    const int*   ei     = (const int*)d_in[1];
    const float* attr   = (const float*)d_in[2];
    const float* emb    = (const float*)d_in[3];
    const float* w1     = (const float*)d_in[4];
    const float* w2     = (const float*)d_in[5];
    const float* w_node = (const float*)d_in[6];

    const int N = in_sizes[0] / 8;   // 50000
    const int E = in_sizes[2] / 4;   // 800000

    float* x_out    = (float*)d_out;                   // [N,16]
    float* edge_out = (float*)d_out + (size_t)N * 16;  // [E,8]
    float* e_sum    = (float*)d_ws;                    // [N,8]

    hipMemsetAsync(e_sum, 0, (size_t)N * 8 * sizeof(float), stream);

    edge_kernel<<<NBLK, TB, 0, stream>>>(x, ei, attr, emb, w1, w2,
                                         edge_out, e_sum, E);

    node_kernel<<<(N + 255) / 256, 256, 0, stream>>>(x, e_sum, w_node, x_out, N);
}